// Round 5
// baseline (392.484 us; speedup 1.0000x reference)
//
#include <hip/hip_runtime.h>
#include <stdint.h>

typedef __attribute__((ext_vector_type(8))) short bhalf8;
typedef __attribute__((ext_vector_type(4))) float fx4;

__device__ __forceinline__ unsigned short f2bf(float f) {
    unsigned u = __builtin_bit_cast(unsigned, f);
    unsigned r = (u + 0x7fffu + ((u >> 16) & 1u)) >> 16;
    return (unsigned short)r;
}
__device__ __forceinline__ float bf2f(unsigned short h) {
    unsigned u = ((unsigned)h) << 16;
    return __builtin_bit_cast(float, u);
}
__device__ __forceinline__ float lrelu(float v) { return v > 0.f ? v : 0.2f * v; }

typedef __attribute__((address_space(1))) void as1_void;
typedef __attribute__((address_space(3))) void as3_void;
__device__ __forceinline__ void gl_lds16(const void* g, void* l) {
    __builtin_amdgcn_global_load_lds((as1_void*)(void*)g, (as3_void*)l, 16, 0, 0);
}

// ---------------- styles: s = w @ a^T + b  (one wave per output) ----------------
__global__ __launch_bounds__(256) void style_kernel(
    const float* __restrict__ w,
    const float* __restrict__ a1w, const float* __restrict__ a1b,
    const float* __restrict__ a2w, const float* __restrict__ a2b,
    const float* __restrict__ a3w, const float* __restrict__ a3b,
    float* __restrict__ s1, float* __restrict__ s2, float* __restrict__ s3)
{
    int gw = blockIdx.x * 4 + (threadIdx.x >> 6);   // 0..4095
    int lane = threadIdx.x & 63;
    int b = gw >> 10, r = gw & 1023;
    const float* arow; const float* abias; float* dst;
    if (r < 512)      { arow = a1w + (size_t)r * 512;        abias = a1b + r;       dst = s1 + b * 512 + r; }
    else if (r < 768) { int rr = r - 512; arow = a2w + (size_t)rr * 512; abias = a2b + rr; dst = s2 + b * 256 + rr; }
    else              { int rr = r - 768; arow = a3w + (size_t)rr * 512; abias = a3b + rr; dst = s3 + b * 256 + rr; }
    const float* wrow = w + b * 512;
    float acc = 0.f;
    #pragma unroll
    for (int j = 0; j < 8; ++j) {
        int c = lane + j * 64;
        acc += wrow[c] * arow[c];
    }
    #pragma unroll
    for (int off = 32; off; off >>= 1) acc += __shfl_down(acc, off, 64);
    if (lane == 0) *dst = acc + *abias;
}

// ---------------- demod: d[b,o] = rsqrt(sum_{i,tap}(w*s)^2 + eps) ----------------
__global__ __launch_bounds__(256) void demod_kernel(
    const float* __restrict__ w1, const float* __restrict__ w2,
    const float* __restrict__ s1, const float* __restrict__ s2,
    float* __restrict__ d1, float* __restrict__ d2)
{
    int blk = blockIdx.x;                 // 2048 blocks
    int conv = blk >> 10, b = (blk >> 8) & 3, o = blk & 255;
    int t = threadIdx.x;
    int cin = conv ? 256 : 512;
    const float* s = conv ? (s2 + b * 256) : (s1 + b * 512);
    const float* row = (conv ? w2 : w1) + (size_t)o * cin * 9;
    __shared__ float sv[512];
    for (int i = t; i < cin; i += 256) { float v = s[i]; sv[i] = v * v; }
    __syncthreads();
    float sum = 0.f;
    int n = cin * 9;
    for (int k = t; k < n; k += 256) {
        float v = row[k];
        sum += v * v * sv[k / 9];
    }
    #pragma unroll
    for (int off = 32; off; off >>= 1) sum += __shfl_down(sum, off, 64);
    __shared__ float red[4];
    if ((t & 63) == 0) red[t >> 6] = sum;
    __syncthreads();
    if (t == 0) {
        float tot = red[0] + red[1] + red[2] + red[3];
        (conv ? d2 : d1)[b * 256 + o] = rsqrtf(tot + 1e-8f);
    }
}

// ---------------- pack weights to bf16, fragment-linear layout ----------------
// layout: [mblk][dy][ic][dx][kh][m(128)][e(8)]
__global__ __launch_bounds__(256) void pack_kernel(
    const float* __restrict__ w1, const float* __restrict__ w2,
    unsigned short* __restrict__ wp1, unsigned short* __restrict__ wp2)
{
    int tid = blockIdx.x * 256 + threadIdx.x;
    const int N1 = 1179648, N2 = 589824;
    if (tid < N1) {
        int e = tid & 7, m = (tid >> 3) & 127, kh = (tid >> 10) & 3;
        int dx = (tid >> 12) % 3, ic = (tid / 12288) & 15;
        int dy = (tid / 196608) % 3, mblk = tid / 589824;
        int o = mblk * 128 + m, ci = ic * 32 + kh * 8 + e;
        wp1[tid] = f2bf(w1[((size_t)o * 512 + ci) * 9 + dy * 3 + dx]);
    } else if (tid < N1 + N2) {
        int t2 = tid - N1;
        int e = t2 & 7, m = (t2 >> 3) & 127, kh = (t2 >> 10) & 3;
        int dx = (t2 >> 12) % 3, ic = (t2 / 12288) & 7;
        int dy = (t2 / 98304) % 3, mblk = t2 / 294912;
        int o = mblk * 128 + m, ci = ic * 32 + kh * 8 + e;
        wp2[t2] = f2bf(w2[((size_t)o * 256 + ci) * 9 + dy * 3 + dx]);
    }
}

// ---------------- bilinear 2x upsample + s1 modulate -> bf16 channels-last ----------------
__global__ __launch_bounds__(256) void upsample_kernel(
    const float* __restrict__ x, const float* __restrict__ s1,
    unsigned short* __restrict__ xu)   // [4][128][128][512]
{
    __shared__ float L[2][64][65];
    int bid = blockIdx.x, t = threadIdx.x;
    int yo = bid & 127, b = bid >> 7;
    int k = yo >> 1;
    int sy0, sy1; float wy0, wy1;
    if ((yo & 1) == 0) { sy0 = k > 0 ? k - 1 : 0; sy1 = k; wy0 = 0.25f; wy1 = 0.75f; }
    else               { sy0 = k; sy1 = k < 63 ? k + 1 : 63; wy0 = 0.75f; wy1 = 0.25f; }
    for (int c0 = 0; c0 < 512; c0 += 64) {
        __syncthreads();
        #pragma unroll
        for (int j = 0; j < 32; ++j) {      // stage 2 rows x 64 c x 64 px
            int f = t + j * 256;
            int idx = f & 63, rowid = f >> 6;
            int cc = rowid & 63, which = rowid >> 6;
            int sy = which ? sy1 : sy0;
            L[which][cc][idx] = x[((size_t)(b * 512 + c0 + cc) * 64 + sy) * 64 + idx];
        }
        __syncthreads();
        #pragma unroll
        for (int j = 0; j < 16; ++j) {      // 128 x * 32 cpairs
            int it = t + j * 256;
            int cp = it & 31, xo = it >> 5;
            int kk = xo >> 1, sx0, sx1; float wx0, wx1;
            if ((xo & 1) == 0) { sx0 = kk > 0 ? kk - 1 : 0; sx1 = kk; wx0 = 0.25f; wx1 = 0.75f; }
            else               { sx0 = kk; sx1 = kk < 63 ? kk + 1 : 63; wx0 = 0.75f; wx1 = 0.25f; }
            int c = cp * 2;
            float A0 = wx0 * L[0][c][sx0] + wx1 * L[0][c][sx1];
            float B0 = wx0 * L[1][c][sx0] + wx1 * L[1][c][sx1];
            float A1 = wx0 * L[0][c + 1][sx0] + wx1 * L[0][c + 1][sx1];
            float B1 = wx0 * L[1][c + 1][sx0] + wx1 * L[1][c + 1][sx1];
            float v0 = (wy0 * A0 + wy1 * B0) * s1[b * 512 + c0 + c];
            float v1 = (wy0 * A1 + wy1 * B1) * s1[b * 512 + c0 + c + 1];
            unsigned pk = (unsigned)f2bf(v0) | ((unsigned)f2bf(v1) << 16);
            *(unsigned*)&xu[((size_t)(b * 128 + yo) * 128 + xo) * 512 + c0 + c] = pk;
        }
    }
}

// ---------------- 3x3 conv, implicit im2col, bf16 MFMA 16x16x32, pipelined ----------------
// Block: 512 thr = 8 waves (oh2 x row2 x wn2). Tile: 256 Cout x 256 px (2 rows).
// Wave-tile: 128 Cout (8 mt) x 64 px (4 nt). Grid 256 = 1 block/CU.
// A double-buffered (2x48KB); B rows restaged in place on dy schedule.
// Each phase: sync -> issue async loads for phase+1 -> compute -> (next sync).
template<int CIN, bool IS_CONV2>
__global__ __launch_bounds__(512, 2) void conv3x3_kernel(
    const unsigned short* __restrict__ inp,
    const unsigned short* __restrict__ wpack,
    const float* __restrict__ dvec,
    const float* __restrict__ bias,
    const float* __restrict__ post,
    unsigned short* __restrict__ outmod,
    float* __restrict__ outf)
{
    constexpr int NIC = CIN / 32;
    __shared__ __attribute__((aligned(16))) short Alds[2][2][12288];  // [buf][mblk][dx*4096+kh*1024+m*8+e] 98304B
    __shared__ __attribute__((aligned(16))) short Blds[4][4160];      // 4 rows x [slot130][8x8 swz] 33280B
    const int tid = threadIdx.x;
    const int lane = tid & 63;
    const int wvi = tid >> 6;          // 0..7
    const int oh = wvi >> 2;           // which 128-Cout half
    const int row = (wvi >> 1) & 1;    // which output row
    const int wn = (wvi & 1) * 64;     // px quarter base
    const int bid = blockIdx.x;        // 256 = b(4) x y2(64)
    const int y0 = (bid & 63) << 1;
    const int b = bid >> 6;
    const int lhi = lane >> 4;
    const int llo = lane & 15;

    auto stageA = [&](int bufp, int ic, int dy) {
        const unsigned short* s0 = wpack + ((size_t)(0 + dy) * NIC + ic) * 12288;
        const unsigned short* s1 = wpack + ((size_t)(3 + dy) * NIC + ic) * 12288;
        #pragma unroll
        for (int j = 0; j < 3; ++j) {
            int g = tid + j * 512;
            gl_lds16(s0 + (size_t)g * 8, (char*)&Alds[bufp][0][0] + g * 16);
        }
        #pragma unroll
        for (int j = 0; j < 3; ++j) {
            int g = tid + j * 512;
            gl_lds16(s1 + (size_t)g * 8, (char*)&Alds[bufp][1][0] + g * 16);
        }
    };
    auto stageB = [&](int r, int ic) {    // one 8KB row, 512 thr x 16B
        int yy = y0 - 1 + r;
        char* dst = (char*)&Blds[r][0] + 64 + tid * 16;
        int xg = tid >> 2, i8 = tid & 3;
        int i8s = i8 ^ ((xg >> 1) & 3);
        if ((unsigned)yy < 128u)
            gl_lds16(inp + ((size_t)(b * 128 + yy) * 128 + xg) * CIN + ic * 32 + i8s * 8, dst);
        else
            *(int4*)dst = make_int4(0, 0, 0, 0);
    };

    if (tid < 32) {   // zero pad slots 0 and 129 of each row buffer (never restaged)
        int r = tid >> 3, sl = (tid >> 2) & 1, part = tid & 3;
        *(int4*)((char*)&Blds[r][0] + (sl ? 8256 : 0) + part * 16) = make_int4(0, 0, 0, 0);
    }

    fx4 acc[8][4];
    #pragma unroll
    for (int mt = 0; mt < 8; ++mt)
        #pragma unroll
        for (int nt = 0; nt < 4; ++nt) acc[mt][nt] = (fx4){0.f, 0.f, 0.f, 0.f};

    // prologue: A(0,0) -> buf0; B rows 0,1 of ic 0
    stageA(0, 0, 0);
    stageB(0, 0);
    stageB(1, 0);
    __syncthreads();

    int buf = 0;
    for (int ic = 0; ic < NIC; ++ic) {
        #pragma unroll
        for (int dy = 0; dy < 3; ++dy) {
            // issue prefetches for the NEXT phase (they drain at this phase's closing sync)
            if (dy == 0) {
                stageA(buf ^ 1, ic, 1);
                stageB(2, ic);
            } else if (dy == 1) {
                stageA(buf ^ 1, ic, 2);
                stageB(3, ic);
                if (ic + 1 < NIC) stageB(0, ic + 1);
            } else {
                if (ic + 1 < NIC) { stageA(buf ^ 1, ic + 1, 0); stageB(1, ic + 1); }
            }
            // compute this phase
            const short* Abase = &Alds[buf][oh][0];
            const short* Brow = &Blds[row + dy][0];
            #pragma unroll
            for (int dx = 0; dx < 3; ++dx) {
                bhalf8 af[8], bfr[4];
                #pragma unroll
                for (int mt = 0; mt < 8; ++mt)
                    af[mt] = *(const bhalf8*)&Abase[dx * 4096 + (lhi * 128 + mt * 16 + llo) * 8];
                #pragma unroll
                for (int nt = 0; nt < 4; ++nt) {
                    int s = wn + nt * 16 + llo + dx;
                    int key = ((s - 1) >> 1) & 3;
                    bfr[nt] = *(const bhalf8*)&Brow[s * 32 + ((lhi ^ key) << 3)];
                }
                #pragma unroll
                for (int mt = 0; mt < 8; ++mt)
                    #pragma unroll
                    for (int nt = 0; nt < 4; ++nt)
                        acc[mt][nt] = __builtin_amdgcn_mfma_f32_16x16x32_bf16(
                            af[mt], bfr[nt], acc[mt][nt], 0, 0, 0);
            }
            __syncthreads();
            buf ^= 1;
        }
    }

    // ---- epilogue: outmod (bf16 channels-last), direct ----
    const int y = y0 + row;
    #pragma unroll
    for (int mt = 0; mt < 8; ++mt) {
        const int o0 = oh * 128 + mt * 16 + lhi * 4;
        const fx4 d4 = *(const fx4*)(dvec + b * 256 + o0);
        const fx4 bb4 = *(const fx4*)(bias + o0);
        const fx4 p4 = *(const fx4*)(post + b * 256 + o0);
        #pragma unroll
        for (int nt = 0; nt < 4; ++nt) {
            const int xo = wn + nt * 16 + llo;
            unsigned lo = 0, hi = 0;
            #pragma unroll
            for (int r = 0; r < 4; ++r) {
                float v = acc[mt][nt][r] * d4[r] + bb4[r];
                v = lrelu(v);
                unsigned short ub = f2bf(v * p4[r]);
                if (r < 2) lo |= (unsigned)ub << (16 * r);
                else       hi |= (unsigned)ub << (16 * (r - 2));
            }
            *(uint2*)&outmod[((size_t)(b * 128 + y) * 128 + xo) * 256 + o0] = make_uint2(lo, hi);
        }
    }

    // ---- epilogue: outf (f32 NCHW) via LDS transpose, fully coalesced ----
    if (IS_CONV2) {
        float* Ef = (float*)&Alds[0][0][0];   // [128 o][132 x-pad] f32 = 67584B, reuses dead A buffers
        #pragma unroll
        for (int ch = 0; ch < 4; ++ch) {
            const int rc = ch >> 1, ohc = ch & 1;
            __syncthreads();
            if (row == rc && oh == ohc) {
                #pragma unroll
                for (int mt = 0; mt < 8; ++mt) {
                    const int o0 = ohc * 128 + mt * 16 + lhi * 4;
                    const fx4 d4 = *(const fx4*)(dvec + b * 256 + o0);
                    const fx4 bb4 = *(const fx4*)(bias + o0);
                    #pragma unroll
                    for (int nt = 0; nt < 4; ++nt) {
                        const int xo = wn + nt * 16 + llo;
                        #pragma unroll
                        for (int r = 0; r < 4; ++r) {
                            float v = lrelu(acc[mt][nt][r] * d4[r] + bb4[r]);
                            Ef[(mt * 16 + lhi * 4 + r) * 132 + xo] = v;
                        }
                    }
                }
            }
            __syncthreads();
            #pragma unroll
            for (int k = 0; k < 8; ++k) {
                int f = k * 8192 + tid * 16;       // bytes within 64KB chunk
                int o_loc = f >> 9, off = f & 511;
                float4 val = *(const float4*)((const char*)Ef + o_loc * 528 + off);
                *(float4*)&outf[(((size_t)b * 256 + ohc * 128 + o_loc) * 128 + (y0 + rc)) * 128 + (off >> 2)] = val;
            }
        }
    }
}

// ---------------- 1x1 to_rgb on h*s3 (bf16), coalesced: 4 lanes per pixel ----------------
__global__ __launch_bounds__(256) void rgb_kernel(
    const unsigned short* __restrict__ hs3,
    const float* __restrict__ w3, const float* __restrict__ b3,
    float* __restrict__ out)   // [4][3][128][128]
{
    __shared__ float wl[768];
    int t = threadIdx.x;
    for (int i = t; i < 768; i += 256) wl[i] = w3[i];
    __syncthreads();
    int p = blockIdx.x * 64 + (t >> 2);   // global pixel 0..65535  (grid = 1024)
    int q = t & 3;                        // channel-quarter
    const unsigned short* src = hs3 + (size_t)p * 256 + q * 64;
    float a0 = 0.f, a1 = 0.f, a2 = 0.f;
    #pragma unroll
    for (int c8 = 0; c8 < 64; c8 += 8) {
        int4 pk = *(const int4*)(src + c8);
        #pragma unroll
        for (int qq = 0; qq < 4; ++qq) {
            unsigned uu = ((const unsigned*)&pk)[qq];
            float ve = bf2f((unsigned short)(uu & 0xffffu));
            float vo = bf2f((unsigned short)(uu >> 16));
            int c = q * 64 + c8 + qq * 2;
            a0 += ve * wl[c] + vo * wl[c + 1];
            a1 += ve * wl[256 + c] + vo * wl[256 + c + 1];
            a2 += ve * wl[512 + c] + vo * wl[512 + c + 1];
        }
    }
    a0 += __shfl_xor(a0, 1, 64); a0 += __shfl_xor(a0, 2, 64);
    a1 += __shfl_xor(a1, 1, 64); a1 += __shfl_xor(a1, 2, 64);
    a2 += __shfl_xor(a2, 1, 64); a2 += __shfl_xor(a2, 2, 64);
    int b = p >> 14, yx = p & 16383;
    if (q < 3) {
        float v = (q == 0) ? a0 : (q == 1) ? a1 : a2;
        out[((size_t)b * 3 + q) * 16384 + yx] = lrelu(v + b3[q]);
    }
}

extern "C" void kernel_launch(void* const* d_in, const int* in_sizes, int n_in,
                              void* d_out, int out_size, void* d_ws, size_t ws_size,
                              hipStream_t stream) {
    const float* x   = (const float*)d_in[0];
    const float* w   = (const float*)d_in[1];
    const float* w1  = (const float*)d_in[2];
    const float* b1  = (const float*)d_in[3];
    const float* a1w = (const float*)d_in[4];
    const float* a1b = (const float*)d_in[5];
    const float* w2  = (const float*)d_in[6];
    const float* b2  = (const float*)d_in[7];
    const float* a2w = (const float*)d_in[8];
    const float* a2b = (const float*)d_in[9];
    const float* w3  = (const float*)d_in[10];
    const float* b3  = (const float*)d_in[11];
    const float* a3w = (const float*)d_in[12];
    const float* a3b = (const float*)d_in[13];

    char* ws = (char*)d_ws;
    unsigned short* xu  = (unsigned short*)(ws);                 // 67108864 B [4][128][128][512] bf16
    unsigned short* hs3 = (unsigned short*)(ws);                 // aliases xu (xu dead after conv1)
    unsigned short* t1  = (unsigned short*)(ws + 67108864);      // 33554432 B [4][128][128][256] bf16
    unsigned short* wp1 = (unsigned short*)(ws + 100663296);     // 2359296 B
    unsigned short* wp2 = (unsigned short*)(ws + 103022592);     // 1179648 B
    float* s1 = (float*)(ws + 104202240);                        // 4*512
    float* s2 = (float*)(ws + 104210432);                        // 4*256
    float* s3 = (float*)(ws + 104214528);                        // 4*256
    float* d1 = (float*)(ws + 104218624);                        // 4*256
    float* d2 = (float*)(ws + 104222720);                        // 4*256

    float* h_out   = (float*)d_out;
    float* rgb_out = h_out + 16777216;

    style_kernel<<<1024, 256, 0, stream>>>(w, a1w, a1b, a2w, a2b, a3w, a3b, s1, s2, s3);
    demod_kernel<<<2048, 256, 0, stream>>>(w1, w2, s1, s2, d1, d2);
    pack_kernel<<<6912, 256, 0, stream>>>(w1, w2, wp1, wp2);
    upsample_kernel<<<512, 256, 0, stream>>>(x, s1, xu);
    conv3x3_kernel<512, false><<<256, 512, 0, stream>>>(xu, wp1, d1, b1, s2, t1, nullptr);
    conv3x3_kernel<256, true><<<256, 512, 0, stream>>>(t1, wp2, d2, b2, s3, hs3, h_out);
    rgb_kernel<<<1024, 256, 0, stream>>>(hs3, w3, b3, rgb_out);
}

// Round 6
// 386.549 us; speedup vs baseline: 1.0154x; 1.0154x over previous
//
#include <hip/hip_runtime.h>
#include <stdint.h>

typedef __attribute__((ext_vector_type(8))) short bhalf8;
typedef __attribute__((ext_vector_type(4))) float fx4;

__device__ __forceinline__ unsigned short f2bf(float f) {
    unsigned u = __builtin_bit_cast(unsigned, f);
    unsigned r = (u + 0x7fffu + ((u >> 16) & 1u)) >> 16;
    return (unsigned short)r;
}
__device__ __forceinline__ float bf2f(unsigned short h) {
    unsigned u = ((unsigned)h) << 16;
    return __builtin_bit_cast(float, u);
}
__device__ __forceinline__ float lrelu(float v) { return v > 0.f ? v : 0.2f * v; }

typedef __attribute__((address_space(1))) void as1_void;
typedef __attribute__((address_space(3))) void as3_void;
__device__ __forceinline__ void gl_lds16(const void* g, void* l) {
    __builtin_amdgcn_global_load_lds((as1_void*)(void*)g, (as3_void*)l, 16, 0, 0);
}

// ---------------- styles: s = w @ a^T + b  (one wave per output) ----------------
__global__ __launch_bounds__(256) void style_kernel(
    const float* __restrict__ w,
    const float* __restrict__ a1w, const float* __restrict__ a1b,
    const float* __restrict__ a2w, const float* __restrict__ a2b,
    const float* __restrict__ a3w, const float* __restrict__ a3b,
    float* __restrict__ s1, float* __restrict__ s2, float* __restrict__ s3)
{
    int gw = blockIdx.x * 4 + (threadIdx.x >> 6);   // 0..4095
    int lane = threadIdx.x & 63;
    int b = gw >> 10, r = gw & 1023;
    const float* arow; const float* abias; float* dst;
    if (r < 512)      { arow = a1w + (size_t)r * 512;        abias = a1b + r;       dst = s1 + b * 512 + r; }
    else if (r < 768) { int rr = r - 512; arow = a2w + (size_t)rr * 512; abias = a2b + rr; dst = s2 + b * 256 + rr; }
    else              { int rr = r - 768; arow = a3w + (size_t)rr * 512; abias = a3b + rr; dst = s3 + b * 256 + rr; }
    const float* wrow = w + b * 512;
    float acc = 0.f;
    #pragma unroll
    for (int j = 0; j < 8; ++j) {
        int c = lane + j * 64;
        acc += wrow[c] * arow[c];
    }
    #pragma unroll
    for (int off = 32; off; off >>= 1) acc += __shfl_down(acc, off, 64);
    if (lane == 0) *dst = acc + *abias;
}

// ---------------- demod: d[b,o] = rsqrt(sum_{i,tap}(w*s)^2 + eps) ----------------
__global__ __launch_bounds__(256) void demod_kernel(
    const float* __restrict__ w1, const float* __restrict__ w2,
    const float* __restrict__ s1, const float* __restrict__ s2,
    float* __restrict__ d1, float* __restrict__ d2)
{
    int blk = blockIdx.x;                 // 2048 blocks
    int conv = blk >> 10, b = (blk >> 8) & 3, o = blk & 255;
    int t = threadIdx.x;
    int cin = conv ? 256 : 512;
    const float* s = conv ? (s2 + b * 256) : (s1 + b * 512);
    const float* row = (conv ? w2 : w1) + (size_t)o * cin * 9;
    __shared__ float sv[512];
    for (int i = t; i < cin; i += 256) { float v = s[i]; sv[i] = v * v; }
    __syncthreads();
    float sum = 0.f;
    int n = cin * 9;
    for (int k = t; k < n; k += 256) {
        float v = row[k];
        sum += v * v * sv[k / 9];
    }
    #pragma unroll
    for (int off = 32; off; off >>= 1) sum += __shfl_down(sum, off, 64);
    __shared__ float red[4];
    if ((t & 63) == 0) red[t >> 6] = sum;
    __syncthreads();
    if (t == 0) {
        float tot = red[0] + red[1] + red[2] + red[3];
        (conv ? d2 : d1)[b * 256 + o] = rsqrtf(tot + 1e-8f);
    }
}

// ---------------- pack weights to bf16, fragment-linear layout ----------------
// layout: [mblk][dy][ic][dx][kh][m(128)][e(8)]
__global__ __launch_bounds__(256) void pack_kernel(
    const float* __restrict__ w1, const float* __restrict__ w2,
    unsigned short* __restrict__ wp1, unsigned short* __restrict__ wp2)
{
    int tid = blockIdx.x * 256 + threadIdx.x;
    const int N1 = 1179648, N2 = 589824;
    if (tid < N1) {
        int e = tid & 7, m = (tid >> 3) & 127, kh = (tid >> 10) & 3;
        int dx = (tid >> 12) % 3, ic = (tid / 12288) & 15;
        int dy = (tid / 196608) % 3, mblk = tid / 589824;
        int o = mblk * 128 + m, ci = ic * 32 + kh * 8 + e;
        wp1[tid] = f2bf(w1[((size_t)o * 512 + ci) * 9 + dy * 3 + dx]);
    } else if (tid < N1 + N2) {
        int t2 = tid - N1;
        int e = t2 & 7, m = (t2 >> 3) & 127, kh = (t2 >> 10) & 3;
        int dx = (t2 >> 12) % 3, ic = (t2 / 12288) & 7;
        int dy = (t2 / 98304) % 3, mblk = t2 / 294912;
        int o = mblk * 128 + m, ci = ic * 32 + kh * 8 + e;
        wp2[t2] = f2bf(w2[((size_t)o * 256 + ci) * 9 + dy * 3 + dx]);
    }
}

// ---------------- bilinear 2x upsample + s1 modulate -> bf16 channels-last ----------------
__global__ __launch_bounds__(256) void upsample_kernel(
    const float* __restrict__ x, const float* __restrict__ s1,
    unsigned short* __restrict__ xu)   // [4][128][128][512]
{
    __shared__ float L[2][64][65];
    int bid = blockIdx.x, t = threadIdx.x;
    int yo = bid & 127, b = bid >> 7;
    int k = yo >> 1;
    int sy0, sy1; float wy0, wy1;
    if ((yo & 1) == 0) { sy0 = k > 0 ? k - 1 : 0; sy1 = k; wy0 = 0.25f; wy1 = 0.75f; }
    else               { sy0 = k; sy1 = k < 63 ? k + 1 : 63; wy0 = 0.75f; wy1 = 0.25f; }
    for (int c0 = 0; c0 < 512; c0 += 64) {
        __syncthreads();
        #pragma unroll
        for (int j = 0; j < 32; ++j) {      // stage 2 rows x 64 c x 64 px
            int f = t + j * 256;
            int idx = f & 63, rowid = f >> 6;
            int cc = rowid & 63, which = rowid >> 6;
            int sy = which ? sy1 : sy0;
            L[which][cc][idx] = x[((size_t)(b * 512 + c0 + cc) * 64 + sy) * 64 + idx];
        }
        __syncthreads();
        #pragma unroll
        for (int j = 0; j < 16; ++j) {      // 128 x * 32 cpairs
            int it = t + j * 256;
            int cp = it & 31, xo = it >> 5;
            int kk = xo >> 1, sx0, sx1; float wx0, wx1;
            if ((xo & 1) == 0) { sx0 = kk > 0 ? kk - 1 : 0; sx1 = kk; wx0 = 0.25f; wx1 = 0.75f; }
            else               { sx0 = kk; sx1 = kk < 63 ? kk + 1 : 63; wx0 = 0.75f; wx1 = 0.25f; }
            int c = cp * 2;
            float A0 = wx0 * L[0][c][sx0] + wx1 * L[0][c][sx1];
            float B0 = wx0 * L[1][c][sx0] + wx1 * L[1][c][sx1];
            float A1 = wx0 * L[0][c + 1][sx0] + wx1 * L[0][c + 1][sx1];
            float B1 = wx0 * L[1][c + 1][sx0] + wx1 * L[1][c + 1][sx1];
            float v0 = (wy0 * A0 + wy1 * B0) * s1[b * 512 + c0 + c];
            float v1 = (wy0 * A1 + wy1 * B1) * s1[b * 512 + c0 + c + 1];
            unsigned pk = (unsigned)f2bf(v0) | ((unsigned)f2bf(v1) << 16);
            *(unsigned*)&xu[((size_t)(b * 128 + yo) * 128 + xo) * 512 + c0 + c] = pk;
        }
    }
}

// ---------------- 3x3 conv, implicit im2col, bf16 MFMA 16x16x32 ----------------
// Block: 256 thr = 4 waves (row2 x wn2), wave-tile 128 Cout (8 mt) x 64 px.
// Tile: 128 Cout x 256 px (2 rows). Grid 512 = 2 blocks/CU (LDS exactly 80 KB).
// A double-buffered (2x24KB, prefetch during compute); B 4 rows x 8KB in-place
// restaged on a race-free schedule: p0 stages rows 2,3(ic); p1 row0(ic+1);
// p2 row1(ic+1). 3 syncs/ic; every load >= 1 phase in flight.
template<int CIN, bool IS_CONV2>
__global__ __launch_bounds__(256, 2) void conv3x3_kernel(
    const unsigned short* __restrict__ inp,
    const unsigned short* __restrict__ wpack,
    const float* __restrict__ dvec,
    const float* __restrict__ bias,
    const float* __restrict__ post,
    unsigned short* __restrict__ outmod,
    float* __restrict__ outf)
{
    constexpr int NIC = CIN / 32;
    __shared__ __attribute__((aligned(16))) short Alds[2][12288];  // 2 x [dx][kh][m128][e8] 49152 B
    __shared__ __attribute__((aligned(16))) short Blds[4][4096];   // 4 rows x [x128][8x8 swz] 32768 B
    const int tid = threadIdx.x;
    const int lane = tid & 63;
    const int wvi = tid >> 6;          // 0..3
    const int row = wvi >> 1;          // output row within tile
    const int wn = (wvi & 1) * 64;     // px half
    const int bid = blockIdx.x;        // 512 = b(4) x mblk(2) x y2(64)
    const int y0 = (bid & 63) << 1;
    const int mblk = (bid >> 6) & 1;
    const int b = bid >> 7;
    const int lhi = lane >> 4;
    const int llo = lane & 15;

    auto stageA = [&](int bufp, int ic, int dy) {
        const unsigned short* src = wpack + ((size_t)(mblk * 3 + dy) * NIC + ic) * 12288;
        #pragma unroll
        for (int j = 0; j < 6; ++j) {
            int g = tid + j * 256;
            gl_lds16(src + (size_t)g * 8, (char*)&Alds[bufp][0] + g * 16);
        }
    };
    auto stageB_row = [&](int r, int ic) {   // one 8 KB row
        int yy = y0 - 1 + r;
        #pragma unroll
        for (int j = 0; j < 2; ++j) {
            int g = tid + j * 256;
            int xg = g >> 2, i8 = g & 3;
            int i8s = i8 ^ ((xg >> 1) & 3);
            char* dst = (char*)&Blds[r][0] + g * 16;
            if ((unsigned)yy < 128u)
                gl_lds16(inp + ((size_t)(b * 128 + yy) * 128 + xg) * CIN + ic * 32 + i8s * 8, dst);
            else
                *(int4*)dst = make_int4(0, 0, 0, 0);
        }
    };

    fx4 acc[8][4];
    #pragma unroll
    for (int mt = 0; mt < 8; ++mt)
        #pragma unroll
        for (int nt = 0; nt < 4; ++nt) acc[mt][nt] = (fx4){0.f, 0.f, 0.f, 0.f};

    // prologue: A(ic0,dy0)->buf0; B rows 0,1 of ic0 (rows 2,3 staged at p0)
    stageA(0, 0, 0);
    stageB_row(0, 0);
    stageB_row(1, 0);
    __syncthreads();

    for (int ic = 0; ic < NIC; ++ic) {
        #pragma unroll
        for (int p = 0; p < 3; ++p) {       // dy == p
            const int buf = (ic + p) & 1;
            // prefetches for future phases (all race-free: targets dead >= 1 sync ago)
            if (p < 2) stageA(buf ^ 1, ic, p + 1);
            else if (ic + 1 < NIC) stageA(buf ^ 1, ic + 1, 0);
            if (p == 0) { stageB_row(2, ic); stageB_row(3, ic); }
            else if (ic + 1 < NIC) {
                if (p == 1) stageB_row(0, ic + 1);
                else        stageB_row(1, ic + 1);
            }
            // compute phase: dy = p, reads Blds[row + p], Alds[buf]
            const short* Abase = &Alds[buf][0];
            const short* Brow  = &Blds[row + p][0];
            #pragma unroll
            for (int dx = 0; dx < 3; ++dx) {
                bhalf8 af[8], bfr[4];
                #pragma unroll
                for (int mt = 0; mt < 8; ++mt)
                    af[mt] = *(const bhalf8*)&Abase[dx * 4096 + lhi * 1024 + (mt * 16 + llo) * 8];
                #pragma unroll
                for (int nt = 0; nt < 4; ++nt) {
                    int x = wn + nt * 16 + llo + dx - 1;
                    int xs = x < 0 ? 0 : (x > 127 ? 127 : x);
                    int key = (xs >> 1) & 3;
                    bfr[nt] = *(const bhalf8*)&Brow[xs * 32 + ((lhi ^ key) << 3)];
                    if (dx != 1) {
                        if (x != xs) { bhalf8 z = {0,0,0,0,0,0,0,0}; bfr[nt] = z; }
                    }
                }
                #pragma unroll
                for (int mt = 0; mt < 8; ++mt)
                    #pragma unroll
                    for (int nt = 0; nt < 4; ++nt)
                        acc[mt][nt] = __builtin_amdgcn_mfma_f32_16x16x32_bf16(
                            af[mt], bfr[nt], acc[mt][nt], 0, 0, 0);
            }
            __syncthreads();
        }
    }

    // ---- epilogue: outmod (bf16 channels-last), direct ----
    const int y = y0 + row;
    #pragma unroll
    for (int mt = 0; mt < 8; ++mt) {
        const int o0 = mblk * 128 + mt * 16 + lhi * 4;
        const fx4 d4 = *(const fx4*)(dvec + b * 256 + o0);
        const fx4 bb4 = *(const fx4*)(bias + o0);
        const fx4 p4 = *(const fx4*)(post + b * 256 + o0);
        #pragma unroll
        for (int nt = 0; nt < 4; ++nt) {
            const int xo = wn + nt * 16 + llo;
            unsigned lo = 0, hi = 0;
            #pragma unroll
            for (int r = 0; r < 4; ++r) {
                float v = acc[mt][nt][r] * d4[r] + bb4[r];
                v = lrelu(v);
                unsigned short ub = f2bf(v * p4[r]);
                if (r < 2) lo |= (unsigned)ub << (16 * r);
                else       hi |= (unsigned)ub << (16 * (r - 2));
            }
            *(uint2*)&outmod[((size_t)(b * 128 + y) * 128 + xo) * 256 + o0] = make_uint2(lo, hi);
        }
    }

    // ---- epilogue: outf (f32 NCHW) via LDS transpose, fully coalesced ----
    if (IS_CONV2) {
        float* Ef = (float*)&Alds[0][0];   // [64 o][132 x] f32 = 33792 B, reuses dead A buffers
        #pragma unroll
        for (int ch = 0; ch < 4; ++ch) {
            const int rc = ch >> 1, oh2 = ch & 1;
            __syncthreads();
            if (row == rc) {
                #pragma unroll
                for (int mi = 0; mi < 4; ++mi) {
                    const int mt = oh2 * 4 + mi;
                    const int ol = mblk * 128 + mt * 16 + lhi * 4;
                    const fx4 d4 = *(const fx4*)(dvec + b * 256 + ol);
                    const fx4 bb4 = *(const fx4*)(bias + ol);
                    #pragma unroll
                    for (int nt = 0; nt < 4; ++nt) {
                        const int xo = wn + nt * 16 + llo;
                        #pragma unroll
                        for (int r = 0; r < 4; ++r) {
                            float v = lrelu(acc[mt][nt][r] * d4[r] + bb4[r]);
                            Ef[(mi * 16 + lhi * 4 + r) * 132 + xo] = v;
                        }
                    }
                }
            }
            __syncthreads();
            #pragma unroll
            for (int k = 0; k < 8; ++k) {
                int f = k * 256 + tid;          // 2048 float4 = 64 o x 128 px
                int o_loc = f >> 5, xq = f & 31;
                float4 val = *(const float4*)&Ef[o_loc * 132 + xq * 4];
                *(float4*)&outf[(((size_t)b * 256 + mblk * 128 + oh2 * 64 + o_loc) * 128 + (y0 + rc)) * 128 + xq * 4] = val;
            }
        }
    }
}

// ---------------- 1x1 to_rgb on h*s3 (bf16), coalesced: 4 lanes per pixel ----------------
__global__ __launch_bounds__(256) void rgb_kernel(
    const unsigned short* __restrict__ hs3,
    const float* __restrict__ w3, const float* __restrict__ b3,
    float* __restrict__ out)   // [4][3][128][128]
{
    __shared__ float wl[768];
    int t = threadIdx.x;
    for (int i = t; i < 768; i += 256) wl[i] = w3[i];
    __syncthreads();
    int p = blockIdx.x * 64 + (t >> 2);   // global pixel 0..65535  (grid = 1024)
    int q = t & 3;                        // channel-quarter
    const unsigned short* src = hs3 + (size_t)p * 256 + q * 64;
    float a0 = 0.f, a1 = 0.f, a2 = 0.f;
    #pragma unroll
    for (int c8 = 0; c8 < 64; c8 += 8) {
        int4 pk = *(const int4*)(src + c8);
        #pragma unroll
        for (int qq = 0; qq < 4; ++qq) {
            unsigned uu = ((const unsigned*)&pk)[qq];
            float ve = bf2f((unsigned short)(uu & 0xffffu));
            float vo = bf2f((unsigned short)(uu >> 16));
            int c = q * 64 + c8 + qq * 2;
            a0 += ve * wl[c] + vo * wl[c + 1];
            a1 += ve * wl[256 + c] + vo * wl[256 + c + 1];
            a2 += ve * wl[512 + c] + vo * wl[512 + c + 1];
        }
    }
    a0 += __shfl_xor(a0, 1, 64); a0 += __shfl_xor(a0, 2, 64);
    a1 += __shfl_xor(a1, 1, 64); a1 += __shfl_xor(a1, 2, 64);
    a2 += __shfl_xor(a2, 1, 64); a2 += __shfl_xor(a2, 2, 64);
    int b = p >> 14, yx = p & 16383;
    if (q < 3) {
        float v = (q == 0) ? a0 : (q == 1) ? a1 : a2;
        out[((size_t)b * 3 + q) * 16384 + yx] = lrelu(v + b3[q]);
    }
}

extern "C" void kernel_launch(void* const* d_in, const int* in_sizes, int n_in,
                              void* d_out, int out_size, void* d_ws, size_t ws_size,
                              hipStream_t stream) {
    const float* x   = (const float*)d_in[0];
    const float* w   = (const float*)d_in[1];
    const float* w1  = (const float*)d_in[2];
    const float* b1  = (const float*)d_in[3];
    const float* a1w = (const float*)d_in[4];
    const float* a1b = (const float*)d_in[5];
    const float* w2  = (const float*)d_in[6];
    const float* b2  = (const float*)d_in[7];
    const float* a2w = (const float*)d_in[8];
    const float* a2b = (const float*)d_in[9];
    const float* w3  = (const float*)d_in[10];
    const float* b3  = (const float*)d_in[11];
    const float* a3w = (const float*)d_in[12];
    const float* a3b = (const float*)d_in[13];

    char* ws = (char*)d_ws;
    unsigned short* xu  = (unsigned short*)(ws);                 // 67108864 B [4][128][128][512] bf16
    unsigned short* hs3 = (unsigned short*)(ws);                 // aliases xu (xu dead after conv1)
    unsigned short* t1  = (unsigned short*)(ws + 67108864);      // 33554432 B [4][128][128][256] bf16
    unsigned short* wp1 = (unsigned short*)(ws + 100663296);     // 2359296 B
    unsigned short* wp2 = (unsigned short*)(ws + 103022592);     // 1179648 B
    float* s1 = (float*)(ws + 104202240);                        // 4*512
    float* s2 = (float*)(ws + 104210432);                        // 4*256
    float* s3 = (float*)(ws + 104214528);                        // 4*256
    float* d1 = (float*)(ws + 104218624);                        // 4*256
    float* d2 = (float*)(ws + 104222720);                        // 4*256

    float* h_out   = (float*)d_out;
    float* rgb_out = h_out + 16777216;

    style_kernel<<<1024, 256, 0, stream>>>(w, a1w, a1b, a2w, a2b, a3w, a3b, s1, s2, s3);
    demod_kernel<<<2048, 256, 0, stream>>>(w1, w2, s1, s2, d1, d2);
    pack_kernel<<<6912, 256, 0, stream>>>(w1, w2, wp1, wp2);
    upsample_kernel<<<512, 256, 0, stream>>>(x, s1, xu);
    conv3x3_kernel<512, false><<<512, 256, 0, stream>>>(xu, wp1, d1, b1, s2, t1, nullptr);
    conv3x3_kernel<256, true><<<512, 256, 0, stream>>>(t1, wp2, d2, b2, s3, hs3, h_out);
    rgb_kernel<<<1024, 256, 0, stream>>>(hs3, w3, b3, rgb_out);
}